// Round 4
// baseline (26776.895 us; speedup 1.0000x reference)
//
#include <hip/hip_runtime.h>

// Tanh RNN: B=64, S=2048, I=H=512, fp32 in/out.
//
// rnn structure (round 4): 16 WGs = 8 pairs. Pair r owns batch rows r*8..r*8+8;
// halves c=0/1 own output cols c*256..+256 with their W_hh halves REGISTER-
// resident (128 VGPR/wave). Per step, a WG needs all 512 h-cols as MFMA-K:
// own 256 from LDS (intra-WG), peer 256 from a write-once global slot.
// Pair (blockIdx b, b+8) lands on the same XCD (round-robin %8) -> peer
// exchange via plain L2 stores + sc0 polls (~100-200cy), with agent-scope
// double-stores + sticky agent-scope poll fallback for placement-independent
// correctness (slow but correct if the mapping ever changes).

typedef _Float16 half8 __attribute__((ext_vector_type(8)));
typedef _Float16 half4 __attribute__((ext_vector_type(4)));
typedef float f32x4 __attribute__((ext_vector_type(4)));
typedef unsigned int u32x4 __attribute__((ext_vector_type(4)));
typedef unsigned long long u64;

#define S_SZ 2048
#define OUT1_OFF 67108864ull   // S*B*H floats

// workspace offsets (bytes); identical footprint to round 3 (~269.55 MB)
#define XP_OFF    0ull              // 2048*64*512*2   = 134217728
#define SLOT_OFF  134217728ull      // 2049*16*512*8   = 134283264
#define WHH_OFF   268500992ull      // 524288
#define WIH_OFF   269025280ull      // 524288
#define BIAS_OFF  269549568ull      // 2048

#define POISON    0x7FFF7FFF7FFF7FFFull
#define POISON32  0x7FFF7FFFu

__device__ __forceinline__ float fast_tanh(float x) {
    float a = exp2f(fminf(fmaxf(x * 2.8853900817779268f, -30.f), 30.f));
    return (a - 1.0f) * __builtin_amdgcn_rcpf(a + 1.0f);
}

// b128 load bypassing L1, cacheable in L2 (XCD-local coherence point)
__device__ __forceinline__ u32x4 load_b128_sc0(const u64* p) {
    u32x4 r;
    asm volatile("global_load_dwordx4 %0, %1, off sc0" : "=v"(r) : "v"(p) : "memory");
    return r;
}

__global__ void prep_kernel(const float* __restrict__ wih, const float* __restrict__ whh,
                            const float* __restrict__ bih, const float* __restrict__ bhh,
                            _Float16* __restrict__ wih16, _Float16* __restrict__ whh16,
                            float* __restrict__ bias)
{
    const int i = blockIdx.x * 256 + threadIdx.x;   // 1024 blocks -> 262144
    wih16[i] = (_Float16)wih[i];
    whh16[i] = (_Float16)whh[i];
    if (i < 512) bias[i] = bih[i] + bhh[i];
}

// poison all 2049*16 slots; slot0 (first 8192 qwords) = packed fp16 state.
// slot(t, r, c) base qword = (t*16 + r*2 + c)*512; layout [8 rows][64 qwords].
__global__ void slotinit_kernel(const float* __restrict__ state, u64* __restrict__ slotq)
{
    const int base = (blockIdx.x * 256 + threadIdx.x) * 4;   // 16392 blocks
    #pragma unroll
    for (int k = 0; k < 4; ++k) {
        const int q = base + k;
        if (q >= 16785408) return;
        if (q < 8192) {
            const int rc = q >> 9, within = q & 511;
            const int r = rc >> 1, c = rc & 1;
            const int brow = within >> 6, j4 = within & 63;
            const float4 v = *reinterpret_cast<const float4*>(
                state + (size_t)(r * 8 + brow) * 512 + c * 256 + j4 * 4);
            union { _Float16 h[4]; u64 u; } p;
            p.h[0] = (_Float16)v.x; p.h[1] = (_Float16)v.y;
            p.h[2] = (_Float16)v.z; p.h[3] = (_Float16)v.w;
            slotq[q] = p.u;
        } else {
            slotq[q] = POISON;
        }
    }
}

// ---------------- input projection GEMM (verified round 3) ----------------
__global__ __launch_bounds__(512, 1) void xproj_kernel(
    const float* __restrict__ inputs, const _Float16* __restrict__ wih16,
    const float* __restrict__ bias, _Float16* __restrict__ xp16)
{
    __shared__ _Float16 Alds[64 * 512];
    const int s = blockIdx.x;

    for (int idx = threadIdx.x; idx < 64 * 128; idx += 512) {
        const int row = idx >> 7, chunk = idx & 127;
        const float4 v = *reinterpret_cast<const float4*>(
            inputs + ((size_t)row * S_SZ + s) * 512 + chunk * 4);
        half4 hv;
        hv[0] = (_Float16)v.x; hv[1] = (_Float16)v.y;
        hv[2] = (_Float16)v.z; hv[3] = (_Float16)v.w;
        const int bc = (chunk * 8) ^ ((row & 7) << 4);
        *reinterpret_cast<half4*>(reinterpret_cast<char*>(Alds) + row * 1024 + bc) = hv;
    }
    __syncthreads();

    const int lane = threadIdx.x & 63, w = threadIdx.x >> 6;
    const int l15 = lane & 15, lg = lane >> 4;

    f32x4 acc[4][4];
    #pragma unroll
    for (int m = 0; m < 4; ++m)
        #pragma unroll
        for (int n = 0; n < 4; ++n)
            acc[m][n] = 0.0f;

    for (int kk = 0; kk < 16; ++kk) {
        half8 af[4], bf[4];
        #pragma unroll
        for (int m = 0; m < 4; ++m) {
            const int row = m * 16 + l15;
            const int bc = (kk * 64 + lg * 16) ^ ((row & 7) << 4);
            af[m] = *reinterpret_cast<const half8*>(
                reinterpret_cast<const char*>(Alds) + row * 1024 + bc);
        }
        #pragma unroll
        for (int n = 0; n < 4; ++n) {
            const int col = w * 64 + n * 16 + l15;
            bf[n] = *reinterpret_cast<const half8*>(wih16 + (size_t)col * 512 + kk * 32 + lg * 8);
        }
        #pragma unroll
        for (int m = 0; m < 4; ++m)
            #pragma unroll
            for (int n = 0; n < 4; ++n)
                acc[m][n] = __builtin_amdgcn_mfma_f32_16x16x32_f16(bf[n], af[m], acc[m][n], 0, 0, 0);
    }

    #pragma unroll
    for (int m = 0; m < 4; ++m) {
        const int brow = m * 16 + l15;
        #pragma unroll
        for (int n = 0; n < 4; ++n) {
            const int j0 = w * 64 + n * 16 + lg * 4;
            const float4 bv = *reinterpret_cast<const float4*>(bias + j0);
            half4 hv;
            hv[0] = (_Float16)(acc[m][n][0] + bv.x);
            hv[1] = (_Float16)(acc[m][n][1] + bv.y);
            hv[2] = (_Float16)(acc[m][n][2] + bv.z);
            hv[3] = (_Float16)(acc[m][n][3] + bv.w);
            *reinterpret_cast<half4*>(xp16 + ((size_t)s * 64 + brow) * 512 + j0) = hv;
        }
    }
}

// ---------------- persistent recurrence: paired WGs, L2-local exchange ----------------
__global__ __launch_bounds__(512, 2) void rnn_step_kernel(
    const _Float16* __restrict__ whh16, const _Float16* __restrict__ xp16,
    u64* __restrict__ slotq, float* __restrict__ out)
{
    const int blk = blockIdx.x;           // 0..15
    const int c = blk >> 3, r = blk & 7;  // pair r, half c; peer = same r, c^1 (same XCD under %8 round-robin)
    const int tid = threadIdx.x;
    const int lane = tid & 63, w = tid >> 6;   // 8 waves
    const int l15 = lane & 15, lg = lane >> 4;
    const int row8 = l15 & 7;

    __shared__ _Float16 hbuf[2][8][264];  // own-half h, double-buffered; row stride 528 B

    // register-resident W_hh half: wf[jt][kk] = whh[j = c*256 + w*32 + jt*16 + l15][k = kk*32 + lg*8 ..+8]
    half8 wf[2][16];
    #pragma unroll
    for (int jt = 0; jt < 2; ++jt) {
        const _Float16* wp = whh16 + (size_t)(c * 256 + w * 32 + jt * 16 + l15) * 512 + lg * 8;
        #pragma unroll
        for (int kk = 0; kk < 16; ++kk)
            wf[jt][kk] = *reinterpret_cast<const half8*>(wp + kk * 32);
    }

    // init hbuf[0] from slot0's own half (prefilled by slotinit)
    {
        const int brow = tid >> 6, q4 = tid & 63;   // 8 rows x 64 qwords
        const u64 v = slotq[(size_t)(r * 2 + c) * 512 + brow * 64 + q4];
        *reinterpret_cast<u64*>(reinterpret_cast<char*>(&hbuf[0][0][0]) + brow * 528 + q4 * 8) = v;
    }
    __syncthreads();

    const int peer_rc = r * 2 + (c ^ 1);
    const int my_rc   = r * 2 + c;
    const int qin_off  = row8 * 64 + lg * 2;            // + kk_rel*8
    const int qout_off = l15 * 64 + w * 8 + lg;         // + jt*4   (valid when l15<8)

    bool slow = false;
    long budget = 200000000L;

    #pragma unroll 1
    for (int t = 0; t < S_SZ; ++t) {
        // ---- acquire peer half of h_t ----
        const u64* qin = slotq + (size_t)(t * 16 + peer_rc) * 512 + qin_off;
        u32x4 pv[8];
        if (!slow) {
            int tries = 0;
            for (;;) {
                #pragma unroll
                for (int i = 0; i < 8; ++i) pv[i] = load_b128_sc0(qin + i * 8);
                // flow pv through the waitcnt so uses can't be hoisted above it
                asm volatile("s_waitcnt vmcnt(0)"
                             : "+v"(pv[0]), "+v"(pv[1]), "+v"(pv[2]), "+v"(pv[3]),
                               "+v"(pv[4]), "+v"(pv[5]), "+v"(pv[6]), "+v"(pv[7])
                             :: "memory");
                bool ok = true;
                #pragma unroll
                for (int i = 0; i < 8; ++i) {
                    ok &= !((pv[i][0] == POISON32) & (pv[i][1] == POISON32));
                    ok &= !((pv[i][2] == POISON32) & (pv[i][3] == POISON32));
                }
                if (__all(ok)) break;
                if (++tries > 64) { slow = true; break; }   // sticky fallback (cross-XCD placement)
                if (--budget < 0) break;
            }
        }
        if (slow) {
            for (;;) {
                union { u32x4 v; u64 u[2]; } a[8];
                #pragma unroll
                for (int i = 0; i < 8; ++i) {
                    a[i].u[0] = __hip_atomic_load(qin + i * 8,     __ATOMIC_RELAXED, __HIP_MEMORY_SCOPE_AGENT);
                    a[i].u[1] = __hip_atomic_load(qin + i * 8 + 1, __ATOMIC_RELAXED, __HIP_MEMORY_SCOPE_AGENT);
                }
                bool ok = true;
                #pragma unroll
                for (int i = 0; i < 8; ++i)
                    ok &= (a[i].u[0] != POISON) & (a[i].u[1] != POISON);
                if (__all(ok) || --budget < 0) {
                    #pragma unroll
                    for (int i = 0; i < 8; ++i) pv[i] = a[i].v;
                    break;
                }
            }
        }

        // ---- xp for this step (latency hidden by MFMA phase) ----
        const _Float16* xpb = xp16 + ((size_t)t * 64 + r * 8 + row8) * 512 + c * 256 + w * 32 + lg * 4;
        const u64 xq0 = *reinterpret_cast<const u64*>(xpb);
        const u64 xq1 = *reinterpret_cast<const u64*>(xpb + 16);

        // ---- own-half B-fragments from LDS ----
        half8 ob[8];
        const char* hrd = reinterpret_cast<const char*>(&hbuf[t & 1][0][0]) + row8 * 528 + lg * 16;
        #pragma unroll
        for (int i = 0; i < 8; ++i)
            ob[i] = *reinterpret_cast<const half8*>(hrd + i * 64);

        // ---- MFMA: k-halves: own kk = c*8+i, peer kk = (c^1)*8+i ----
        f32x4 acc0 = 0.0f, acc1 = 0.0f;
        #pragma unroll
        for (int i = 0; i < 8; ++i) {
            acc0 = __builtin_amdgcn_mfma_f32_16x16x32_f16(wf[0][c * 8 + i], ob[i], acc0, 0, 0, 0);
            acc1 = __builtin_amdgcn_mfma_f32_16x16x32_f16(wf[1][c * 8 + i], ob[i], acc1, 0, 0, 0);
            union { u32x4 v; half8 h; } pc; pc.v = pv[i];
            acc0 = __builtin_amdgcn_mfma_f32_16x16x32_f16(wf[0][(c ^ 1) * 8 + i], pc.h, acc0, 0, 0, 0);
            acc1 = __builtin_amdgcn_mfma_f32_16x16x32_f16(wf[1][(c ^ 1) * 8 + i], pc.h, acc1, 0, 0, 0);
        }

        // ---- tanh + pack ----
        union { _Float16 h[4]; u64 u; } x0, x1, p0, p1;
        x0.u = xq0; x1.u = xq1;
        f32x4 f0, f1;
        #pragma unroll
        for (int q = 0; q < 4; ++q) {
            f0[q] = fast_tanh(acc0[q] + (float)x0.h[q]);
            f1[q] = fast_tanh(acc1[q] + (float)x1.h[q]);
            p0.h[q] = (_Float16)f0[q];
            p1.h[q] = (_Float16)f1[q];
        }

        // ---- publish + outputs (real rows only) ----
        if (l15 < 8) {
            u64* qo = slotq + (size_t)((t + 1) * 16 + my_rc) * 512 + qout_off;
            // MALL write-through first (placement-independent correctness) ...
            __hip_atomic_store(qo,     p0.u, __ATOMIC_RELAXED, __HIP_MEMORY_SCOPE_AGENT);
            __hip_atomic_store(qo + 4, p1.u, __ATOMIC_RELAXED, __HIP_MEMORY_SCOPE_AGENT);
            // ... then plain L2 stores (fast path for same-XCD peer; volatile so not elided)
            *reinterpret_cast<volatile u64*>(qo)     = p0.u;
            *reinterpret_cast<volatile u64*>(qo + 4) = p1.u;

            // LDS for next step (own half)
            char* hwr = reinterpret_cast<char*>(&hbuf[(t + 1) & 1][0][0]) + l15 * 528 + (w * 32 + lg * 4) * 2;
            *reinterpret_cast<half4*>(hwr)      = *reinterpret_cast<half4*>(&p0);
            *reinterpret_cast<half4*>(hwr + 32) = *reinterpret_cast<half4*>(&p1);

            // fp32 outputs
            float* orow = out + ((size_t)t * 64 + r * 8 + l15) * 512 + c * 256 + w * 32 + lg * 4;
            *reinterpret_cast<f32x4*>(orow)      = f0;
            *reinterpret_cast<f32x4*>(orow + 16) = f1;

            if (t == S_SZ - 1) {
                const int j0 = c * 256 + w * 32 + lg * 4;
                #pragma unroll
                for (int q = 0; q < 4; ++q) {
                    out[OUT1_OFF + (size_t)(j0 + q) * 64 + (r * 8 + l15)] = f0[q];
                    out[OUT1_OFF + (size_t)(j0 + 16 + q) * 64 + (r * 8 + l15)] = f1[q];
                }
            }
        }

        asm volatile("s_waitcnt lgkmcnt(0)" ::: "memory");
        __builtin_amdgcn_s_barrier();
    }
}

extern "C" void kernel_launch(void* const* d_in, const int* in_sizes, int n_in,
                              void* d_out, int out_size, void* d_ws, size_t ws_size,
                              hipStream_t stream)
{
    const float* inputs = (const float*)d_in[0];
    const float* state  = (const float*)d_in[1];
    const float* w_ih   = (const float*)d_in[2];
    const float* b_ih   = (const float*)d_in[3];
    const float* w_hh   = (const float*)d_in[4];
    const float* b_hh   = (const float*)d_in[5];
    float* out = (float*)d_out;
    char* ws = (char*)d_ws;

    _Float16* xp16  = (_Float16*)(ws + XP_OFF);
    u64*      slotq = (u64*)(ws + SLOT_OFF);
    _Float16* whh16 = (_Float16*)(ws + WHH_OFF);
    _Float16* wih16 = (_Float16*)(ws + WIH_OFF);
    float*    bias  = (float*)(ws + BIAS_OFF);

    slotinit_kernel<<<16392, 256, 0, stream>>>(state, slotq);
    prep_kernel<<<1024, 256, 0, stream>>>(w_ih, w_hh, b_ih, b_hh, wih16, whh16, bias);
    xproj_kernel<<<S_SZ, 512, 0, stream>>>(inputs, wih16, bias, xp16);
    rnn_step_kernel<<<16, 512, 0, stream>>>(whh16, xp16, slotq, out);
}